// Round 4
// baseline (284.071 us; speedup 1.0000x reference)
//
#include <hip/hip_runtime.h>
#include <math.h>

#define BATCH 8
#define SEQ 4096
#define DIMSZ 384
#define HEADS 6
#define DH 64
#define MTOT (BATCH * SEQ) /* 32768 */
#define KD 384

typedef short short8 __attribute__((ext_vector_type(8)));
typedef float floatx4 __attribute__((ext_vector_type(4)));
typedef unsigned short ushort4v __attribute__((ext_vector_type(4)));
typedef unsigned short ushort8v __attribute__((ext_vector_type(8)));

__device__ __forceinline__ float elu1(float x) { return x > 0.f ? x + 1.f : __expf(x); }

__device__ __forceinline__ unsigned short f2b(float f) {
    unsigned int u = __float_as_uint(f);
    u = (u + 0x7fffu + ((u >> 16) & 1u)) >> 16;
    return (unsigned short)u;
}
__device__ __forceinline__ float b2f(unsigned short u) {
    return __uint_as_float(((unsigned int)u) << 16);
}

__device__ __forceinline__ void gl16(const void* g, void* l) {
    __builtin_amdgcn_global_load_lds((const __attribute__((address_space(1))) unsigned int*)g,
                                     (__attribute__((address_space(3))) unsigned int*)l, 16, 0, 0);
}

// ---------------------------------------------------------------------------
// W[384][N] fp32 -> WT[N][384] bf16 (transpose + convert)
// ---------------------------------------------------------------------------
__global__ __launch_bounds__(256) void conv_wt(const float* __restrict__ W,
                                               unsigned short* __restrict__ WT, int N) {
    __shared__ float tile[32][33];
    const int n0 = blockIdx.x * 32, k0 = blockIdx.y * 32;
    const int tx = threadIdx.x & 31, ty = threadIdx.x >> 5;  // 32 x 8
#pragma unroll
    for (int i = 0; i < 32; i += 8) tile[ty + i][tx] = W[(size_t)(k0 + ty + i) * N + n0 + tx];
    __syncthreads();
#pragma unroll
    for (int i = 0; i < 32; i += 8)
        WT[(size_t)(n0 + ty + i) * KD + k0 + tx] = f2b(tile[tx][ty + i]);
}

// ---------------------------------------------------------------------------
// MFMA GEMM: A[M][384] (fp32 if AF32, else bf16) row-major, BT[N][384] bf16,
// 128x128 tile, BK=64. fp32->bf16 conversion fused into A staging.
// XCD-aware 1D swizzle: xcd=id&7 owns row-tiles [xcd*32, xcd*32+32), all
// col-tiles of a row-tile on one XCD -> A-tile fetched once per XCD L2.
// EPI: 0 = elu+1 -> bf16 row-major (LDS-transposed 16B nt stores)
//      2 = +bias -> fp32 row-major (nt scalar stores)
//      3 = (col<384 ? elu+1 : id) -> bf16 TRANSPOSED CT[col][MTOT] (LDS, 16B nt)
// ---------------------------------------------------------------------------
template <int EPI, int NC, bool AF32>
__global__ __launch_bounds__(256) void gemm_bt(const void* __restrict__ Aptr,
                                               const unsigned short* __restrict__ BT,
                                               void* __restrict__ Cout,
                                               const float* __restrict__ bias) {
    __shared__ __align__(16) unsigned short buf[17408];  // As[128][64] | Bs[128][64]; epi tile
    unsigned short* As = buf;
    unsigned short* Bs = buf + 8192;
    const int tid = threadIdx.x;
    const int lane = tid & 63, wave = tid >> 6;
    const int l15 = lane & 15, qd = lane >> 4;
    constexpr int NXT = NC / 128;
    const int fid = blockIdx.x;
    const int xcd = fid & 7;
    const int s = fid >> 3;  // 0 .. NXT*32-1
    const int row0 = (xcd * 32 + s / NXT) * 128;
    const int col0 = (s % NXT) * 128;
    const int wm = (wave & 1) * 64, wn = (wave >> 1) * 64;

    const float* Af = (const float*)Aptr;
    const unsigned short* Ab = (const unsigned short*)Aptr;
    const unsigned short* Bb = BT + (size_t)col0 * KD;
    const int srow = tid >> 3;        // 0..31
    const int scol = (tid & 7) * 8;   // 0..56

    floatx4 zero = {0.f, 0.f, 0.f, 0.f};
    floatx4 acc[4][4];
#pragma unroll
    for (int i = 0; i < 4; ++i)
#pragma unroll
        for (int j = 0; j < 4; ++j) acc[i][j] = zero;

    for (int kk = 0; kk < KD; kk += 64) {
        __syncthreads();
        if (AF32) {
#pragma unroll
            for (int i = 0; i < 4; ++i) {
                const float* src = Af + (size_t)(row0 + i * 32 + srow) * KD + kk + scol;
                float4 a = *(const float4*)src;
                float4 b = *(const float4*)(src + 4);
                ushort8v o;
                o[0] = f2b(a.x); o[1] = f2b(a.y); o[2] = f2b(a.z); o[3] = f2b(a.w);
                o[4] = f2b(b.x); o[5] = f2b(b.y); o[6] = f2b(b.z); o[7] = f2b(b.w);
                *(ushort8v*)&As[(i * 32 + srow) * 64 + scol] = o;
            }
        } else {
#pragma unroll
            for (int i = 0; i < 4; ++i)
                gl16(Ab + (size_t)(row0 + i * 32 + srow) * KD + kk + scol,
                     As + i * 2048 + wave * 512);
        }
#pragma unroll
        for (int i = 0; i < 4; ++i)
            gl16(Bb + (size_t)(i * 32 + srow) * KD + kk + scol, Bs + i * 2048 + wave * 512);
        __syncthreads();
#pragma unroll
        for (int t = 0; t < 2; ++t) {
            short8 af[4], bfr[4];
#pragma unroll
            for (int mi = 0; mi < 4; ++mi)
                af[mi] = *(const short8*)&As[(wm + mi * 16 + l15) * 64 + t * 32 + qd * 8];
#pragma unroll
            for (int ni = 0; ni < 4; ++ni)
                bfr[ni] = *(const short8*)&Bs[(wn + ni * 16 + l15) * 64 + t * 32 + qd * 8];
#pragma unroll
            for (int mi = 0; mi < 4; ++mi)
#pragma unroll
                for (int ni = 0; ni < 4; ++ni)
                    acc[mi][ni] = __builtin_amdgcn_mfma_f32_16x16x32_bf16(af[mi], bfr[ni],
                                                                          acc[mi][ni], 0, 0, 0);
        }
    }

    if (EPI == 2) {
        float* C = (float*)Cout;
#pragma unroll
        for (int mi = 0; mi < 4; ++mi)
#pragma unroll
            for (int ni = 0; ni < 4; ++ni) {
                const int rbase = row0 + wm + mi * 16 + qd * 4;
                const int col = col0 + wn + ni * 16 + l15;
                const float bsv = bias[col];
#pragma unroll
                for (int r = 0; r < 4; ++r)
                    __builtin_nontemporal_store(acc[mi][ni][r] + bsv,
                                                &C[(size_t)(rbase + r) * NC + col]);
            }
    } else {
        __syncthreads();  // K-loop LDS reads done before tile reuse
#pragma unroll
        for (int mi = 0; mi < 4; ++mi)
#pragma unroll
            for (int ni = 0; ni < 4; ++ni) {
                const int rb = wm + mi * 16 + qd * 4;
                const int cl = wn + ni * 16 + l15;
                if (EPI == 0) {
#pragma unroll
                    for (int r = 0; r < 4; ++r)
                        buf[(rb + r) * 136 + cl] = f2b(elu1(acc[mi][ni][r]));
                } else {  // EPI == 3: column-major tile
                    const bool act = (col0 + cl) < DIMSZ;
                    ushort4v o;
#pragma unroll
                    for (int r = 0; r < 4; ++r) {
                        float v = acc[mi][ni][r];
                        o[r] = f2b(act ? elu1(v) : v);
                    }
                    *(ushort4v*)&buf[cl * 136 + rb] = o;
                }
            }
        __syncthreads();
        if (EPI == 0) {
            unsigned short* C = (unsigned short*)Cout;
            const int r0 = tid >> 4, c0 = (tid & 15) * 8;
#pragma unroll
            for (int p = 0; p < 8; ++p) {
                const int row = r0 + p * 16;
                ushort8v v = *(const ushort8v*)&buf[row * 136 + c0];
                __builtin_nontemporal_store(
                    v, (ushort8v*)&C[(size_t)(row0 + row) * NC + col0 + c0]);
            }
        } else {
            unsigned short* CT = (unsigned short*)Cout;
            const int c0 = tid >> 4, rr = (tid & 15) * 8;
#pragma unroll
            for (int p = 0; p < 8; ++p) {
                const int col = c0 + p * 16;
                ushort8v v = *(const ushort8v*)&buf[col * 136 + rr];
                __builtin_nontemporal_store(
                    v, (ushort8v*)&CT[(size_t)(col0 + col) * MTOT + row0 + rr]);
            }
        }
    }
}

// ---------------------------------------------------------------------------
// kv state via MFMA: kv[bh][d][m] = sum_n k[n,d]*v[n,m], ksum fused.
// kvpT[768][MTOT] bf16 (k rows [0,384), v rows [384,768)).
// ---------------------------------------------------------------------------
__global__ __launch_bounds__(256) void kv_state_mfma(const unsigned short* __restrict__ kvpT,
                                                     float* __restrict__ pkv,
                                                     float* __restrict__ pks) {
    __shared__ float kvLDS[4096];
    __shared__ float ksLDS[64];
    const int bx = blockIdx.x;
    const int bh = bx >> 4, ch = bx & 15;
    const int b = bh / HEADS, h = bh % HEADS;
    const int tid = threadIdx.x;
    const int lane = tid & 63, wave = tid >> 6;
    const int l15 = lane & 15, qd = lane >> 4;
    const size_t nbase = (size_t)b * SEQ + ch * 256 + wave * 64;
    const unsigned short* kbase = kvpT + (size_t)(h * 64) * MTOT + nbase;
    const unsigned short* vbase = kvpT + (size_t)(DIMSZ + h * 64) * MTOT + nbase;

    floatx4 zero = {0.f, 0.f, 0.f, 0.f};
    floatx4 acc[4][4];
#pragma unroll
    for (int i = 0; i < 4; ++i)
#pragma unroll
        for (int j = 0; j < 4; ++j) acc[i][j] = zero;
    float ksa[4] = {};

#pragma unroll
    for (int t = 0; t < 2; ++t) {
        short8 af[4], bfr[4];
#pragma unroll
        for (int mi = 0; mi < 4; ++mi)
            af[mi] = *(const short8*)&kbase[(size_t)(mi * 16 + l15) * MTOT + t * 32 + qd * 8];
#pragma unroll
        for (int ni = 0; ni < 4; ++ni)
            bfr[ni] = *(const short8*)&vbase[(size_t)(ni * 16 + l15) * MTOT + t * 32 + qd * 8];
#pragma unroll
        for (int mi = 0; mi < 4; ++mi) {
#pragma unroll
            for (int j = 0; j < 8; ++j) ksa[mi] += b2f((unsigned short)af[mi][j]);
#pragma unroll
            for (int ni = 0; ni < 4; ++ni)
                acc[mi][ni] =
                    __builtin_amdgcn_mfma_f32_16x16x32_bf16(af[mi], bfr[ni], acc[mi][ni], 0, 0, 0);
        }
    }
#pragma unroll
    for (int mi = 0; mi < 4; ++mi) {
        float v = ksa[mi];
        v += __shfl_xor(v, 16);
        v += __shfl_xor(v, 32);
        ksa[mi] = v;
    }
    for (int w = 0; w < 4; ++w) {
        if (wave == w) {
#pragma unroll
            for (int mi = 0; mi < 4; ++mi)
#pragma unroll
                for (int ni = 0; ni < 4; ++ni)
#pragma unroll
                    for (int r = 0; r < 4; ++r) {
                        const int idx = (mi * 16 + qd * 4 + r) * 64 + ni * 16 + l15;
                        if (w == 0) kvLDS[idx] = acc[mi][ni][r];
                        else kvLDS[idx] += acc[mi][ni][r];
                    }
            if (lane < 16) {
#pragma unroll
                for (int mi = 0; mi < 4; ++mi) {
                    if (w == 0) ksLDS[mi * 16 + lane] = ksa[mi];
                    else ksLDS[mi * 16 + lane] += ksa[mi];
                }
            }
        }
        __syncthreads();
    }
    const int base = tid * 16;
#pragma unroll
    for (int i = 0; i < 16; i += 4)
        *(float4*)&pkv[(size_t)bx * 4096 + base + i] = *(float4*)&kvLDS[base + i];
    if (tid < 64) pks[bx * 64 + tid] = ksLDS[tid];
}

// ---------------------------------------------------------------------------
// reduce 16 partials per bh -> kv_g fp32, ksum_g fp32
// ---------------------------------------------------------------------------
__global__ __launch_bounds__(256) void kv_reduce(const float* __restrict__ pkv,
                                                 const float* __restrict__ pks,
                                                 float* __restrict__ kv_g,
                                                 float* __restrict__ ksum_g) {
    const int bh = blockIdx.x;
    const int tid = threadIdx.x;
    for (int i0 = tid * 4; i0 < 4096; i0 += 1024) {
        float4 s = {0.f, 0.f, 0.f, 0.f};
#pragma unroll
        for (int c = 0; c < 16; ++c) {
            float4 p = *(const float4*)&pkv[(size_t)(bh * 16 + c) * 4096 + i0];
            s.x += p.x; s.y += p.y; s.z += p.z; s.w += p.w;
        }
        *(float4*)&kv_g[(size_t)bh * 4096 + i0] = s;
    }
    if (tid < 64) {
        float s = 0.f;
#pragma unroll
        for (int c = 0; c < 16; ++c) s += pks[(bh * 16 + c) * 64 + tid];
        ksum_g[bh * 64 + tid] = s;
    }
}

// ---------------------------------------------------------------------------
// attn[n, h*64+m] = z_n * sum_d q[n,d] kv[bh][d][m]  (MFMA, z fused, in-place)
// ---------------------------------------------------------------------------
__global__ __launch_bounds__(256) void attn_mfma(const unsigned short* __restrict__ q,
                                                 const float* __restrict__ kv_g,
                                                 const float* __restrict__ ksum_g,
                                                 unsigned short* __restrict__ attn) {
    __shared__ __align__(16) unsigned short kvbs[64 * 72];  // [m][d], pad 72
    __shared__ float ksh[64];
    __shared__ float zsh[256];
    const int bx = blockIdx.x;
    const int bh = bx >> 4;
    const int rt = bx & 15;
    const int b = bh / HEADS, h = bh % HEADS;
    const int tid = threadIdx.x;
    const int lane = tid & 63, wave = tid >> 6;
    const int l15 = lane & 15, qd = lane >> 4;
#pragma unroll
    for (int i = 0; i < 16; ++i) {
        int e = i * 256 + tid;
        int d = e >> 6, m = e & 63;
        kvbs[m * 72 + d] = f2b(kv_g[(size_t)bh * 4096 + e]);
    }
    if (tid < 64) ksh[tid] = ksum_g[bh * 64 + tid];
    __syncthreads();
    const size_t rowbase = (size_t)b * SEQ + rt * 256;
    floatx4 zero = {0.f, 0.f, 0.f, 0.f};
    floatx4 acc[4][4];
#pragma unroll
    for (int i = 0; i < 4; ++i)
#pragma unroll
        for (int j = 0; j < 4; ++j) acc[i][j] = zero;
    float zp[4] = {};
#pragma unroll
    for (int ks = 0; ks < 2; ++ks) {
        short8 bfr[4];
#pragma unroll
        for (int ni = 0; ni < 4; ++ni)
            bfr[ni] = *(const short8*)&kvbs[(ni * 16 + l15) * 72 + ks * 32 + qd * 8];
#pragma unroll
        for (int mi = 0; mi < 4; ++mi) {
            short8 af = *(const short8*)&q[(rowbase + wave * 64 + mi * 16 + l15) * KD + h * 64 +
                                           ks * 32 + qd * 8];
#pragma unroll
            for (int j = 0; j < 8; ++j)
                zp[mi] += b2f((unsigned short)af[j]) * ksh[ks * 32 + qd * 8 + j];
#pragma unroll
            for (int ni = 0; ni < 4; ++ni)
                acc[mi][ni] =
                    __builtin_amdgcn_mfma_f32_16x16x32_bf16(af, bfr[ni], acc[mi][ni], 0, 0, 0);
        }
    }
#pragma unroll
    for (int mi = 0; mi < 4; ++mi) {
        float v = zp[mi];
        v += __shfl_xor(v, 16);
        v += __shfl_xor(v, 32);
        if (lane < 16) zsh[wave * 64 + mi * 16 + lane] = 1.f / (v + 1e-6f);
    }
    __syncthreads();
#pragma unroll
    for (int mi = 0; mi < 4; ++mi) {
#pragma unroll
        for (int ni = 0; ni < 4; ++ni) {
            const int rl = wave * 64 + mi * 16 + qd * 4;
            const int col = h * 64 + ni * 16 + l15;
#pragma unroll
            for (int r = 0; r < 4; ++r) {
                float v = acc[mi][ni][r] * zsh[rl + r];
                attn[(rowbase + rl + r) * KD + col] = f2b(v);
            }
        }
    }
}

extern "C" void kernel_launch(void* const* d_in, const int* in_sizes, int n_in,
                              void* d_out, int out_size, void* d_ws, size_t ws_size,
                              hipStream_t stream) {
    const float* x_q = (const float*)d_in[0];
    const float* x_kv = (const float*)d_in[1];
    const float* Wq = (const float*)d_in[2];
    const float* Wkv = (const float*)d_in[3];
    const float* Wout = (const float*)d_in[4];
    const float* bout = (const float*)d_in[5];
    float* out = (float*)d_out;

    char* ws = (char*)d_ws;
    unsigned short* kvpT = (unsigned short*)(ws + 0);          // 50.3 MB [768][32768]
    unsigned short* q_bf = (unsigned short*)(ws + 50331648);   // 25.2 MB (attn in-place)
    unsigned short* WqT = (unsigned short*)(ws + 75497472);    // 0.29 MB
    unsigned short* WkvT = (unsigned short*)(ws + 75792384);   // 0.59 MB
    unsigned short* WoutT = (unsigned short*)(ws + 76382208);  // 0.29 MB
    float* kv = (float*)(ws + 76677120);                       // 0.79 MB
    float* ksum = (float*)(ws + 77463552);                     // 12 KB
    float* pkv = (float*)(ws + 77475840);                      // 12.6 MB
    float* pks = (float*)(ws + 90058752);                      // 0.19 MB

    dim3 blk(256);
    conv_wt<<<dim3(12, 12), blk, 0, stream>>>(Wq, WqT, DIMSZ);
    conv_wt<<<dim3(24, 12), blk, 0, stream>>>(Wkv, WkvT, 2 * DIMSZ);
    conv_wt<<<dim3(12, 12), blk, 0, stream>>>(Wout, WoutT, DIMSZ);
    // kv-projection (fp32 A fused-convert) -> TRANSPOSED kvpT
    gemm_bt<3, 768, true><<<dim3(1536), blk, 0, stream>>>(x_kv, WkvT, kvpT, nullptr);
    // kv state + ksum via MFMA (partials), then reduce
    kv_state_mfma<<<dim3(768), blk, 0, stream>>>(kvpT, pkv, pks);
    kv_reduce<<<dim3(48), blk, 0, stream>>>(pkv, pks, kv, ksum);
    // q-projection (fp32 A fused-convert)
    gemm_bt<0, 384, true><<<dim3(768), blk, 0, stream>>>(x_q, WqT, q_bf, nullptr);
    // attn = (q @ kv) * z   (z fused; in-place over q)
    attn_mfma<<<dim3(768), blk, 0, stream>>>(q_bf, kv, ksum, q_bf);
    // out = attn @ Wout + bout
    gemm_bt<2, 384, false><<<dim3(768), blk, 0, stream>>>(q_bf, WoutT, out, bout);
}

// Round 5
// 277.083 us; speedup vs baseline: 1.0252x; 1.0252x over previous
//
#include <hip/hip_runtime.h>
#include <math.h>

#define BATCH 8
#define SEQ 4096
#define DIMSZ 384
#define HEADS 6
#define DH 64
#define MTOT (BATCH * SEQ) /* 32768 */
#define KD 384

typedef short short8 __attribute__((ext_vector_type(8)));
typedef float floatx4 __attribute__((ext_vector_type(4)));
typedef unsigned short ushort4v __attribute__((ext_vector_type(4)));
typedef unsigned short ushort8v __attribute__((ext_vector_type(8)));

__device__ __forceinline__ float elu1(float x) { return x > 0.f ? x + 1.f : __expf(x); }

__device__ __forceinline__ unsigned short f2b(float f) {
    unsigned int u = __float_as_uint(f);
    u = (u + 0x7fffu + ((u >> 16) & 1u)) >> 16;
    return (unsigned short)u;
}
__device__ __forceinline__ float b2f(unsigned short u) {
    return __uint_as_float(((unsigned int)u) << 16);
}

__device__ __forceinline__ void gl16(const void* g, void* l) {
    __builtin_amdgcn_global_load_lds((const __attribute__((address_space(1))) unsigned int*)g,
                                     (__attribute__((address_space(3))) unsigned int*)l, 16, 0, 0);
}

// ---------------------------------------------------------------------------
// fp32 -> bf16 bulk convert (8 elems/thread) — pure-BW pass; conversion here
// is free (hidden under HBM), unlike fused-in-GEMM (R4 regression).
// ---------------------------------------------------------------------------
__global__ __launch_bounds__(256) void conv_bf16(const float* __restrict__ src,
                                                 unsigned short* __restrict__ dst) {
    size_t i = ((size_t)blockIdx.x * 256 + threadIdx.x) * 8;
    float4 a = *(const float4*)&src[i];
    float4 b = *(const float4*)&src[i + 4];
    ushort8v o;
    o[0] = f2b(a.x); o[1] = f2b(a.y); o[2] = f2b(a.z); o[3] = f2b(a.w);
    o[4] = f2b(b.x); o[5] = f2b(b.y); o[6] = f2b(b.z); o[7] = f2b(b.w);
    *(ushort8v*)&dst[i] = o;
}

// ---------------------------------------------------------------------------
// W[384][N] fp32 -> WT[N][384] bf16 (transpose + convert)
// ---------------------------------------------------------------------------
__global__ __launch_bounds__(256) void conv_wt(const float* __restrict__ W,
                                               unsigned short* __restrict__ WT, int N) {
    __shared__ float tile[32][33];
    const int n0 = blockIdx.x * 32, k0 = blockIdx.y * 32;
    const int tx = threadIdx.x & 31, ty = threadIdx.x >> 5;  // 32 x 8
#pragma unroll
    for (int i = 0; i < 32; i += 8) tile[ty + i][tx] = W[(size_t)(k0 + ty + i) * N + n0 + tx];
    __syncthreads();
#pragma unroll
    for (int i = 0; i < 32; i += 8)
        WT[(size_t)(n0 + ty + i) * KD + k0 + tx] = f2b(tile[tx][ty + i]);
}

// ---------------------------------------------------------------------------
// MFMA GEMM: A[M][384] bf16 row-major, BT[N][384] bf16, 128x128 tile, BK=64,
// global_load_lds-only staging (conflict-free, no VALU).
// XCD swizzle: xcd=id&7 owns row-tile group -> A fetched once per XCD L2.
// EPI: 0 = elu+1 -> bf16 row-major (direct 2B stores)
//      2 = +bias -> fp32 row-major (nt stores, full 64B/quad lines)
//      3 = (col<384 ? elu+1 : id) -> bf16 TRANSPOSED CT[col][MTOT]
//          via LDS transpose + 16B nt stores (kills write-allocate RMW: R4
//          proved FETCH 77->27 MB)
// ---------------------------------------------------------------------------
template <int EPI, int NC>
__global__ __launch_bounds__(256) void gemm_bt(const unsigned short* __restrict__ A,
                                               const unsigned short* __restrict__ BT,
                                               void* __restrict__ Cout,
                                               const float* __restrict__ bias) {
    __shared__ __align__(16) unsigned short buf[17408];  // As[128][64] | Bs[128][64]; epi tile
    unsigned short* As = buf;
    unsigned short* Bs = buf + 8192;
    const int tid = threadIdx.x;
    const int lane = tid & 63, wave = tid >> 6;
    const int l15 = lane & 15, qd = lane >> 4;
    constexpr int NXT = NC / 128;
    const int fid = blockIdx.x;
    const int xcd = fid & 7;
    const int s = fid >> 3;
    const int row0 = (xcd * 32 + s / NXT) * 128;
    const int col0 = (s % NXT) * 128;
    const int wm = (wave & 1) * 64, wn = (wave >> 1) * 64;

    const unsigned short* Ab = A + (size_t)row0 * KD;
    const unsigned short* Bb = BT + (size_t)col0 * KD;
    const int srow = tid >> 3;       // 0..31
    const int scol = (tid & 7) * 8;  // 0..56

    floatx4 zero = {0.f, 0.f, 0.f, 0.f};
    floatx4 acc[4][4];
#pragma unroll
    for (int i = 0; i < 4; ++i)
#pragma unroll
        for (int j = 0; j < 4; ++j) acc[i][j] = zero;

    for (int kk = 0; kk < KD; kk += 64) {
        __syncthreads();
#pragma unroll
        for (int i = 0; i < 4; ++i)
            gl16(Ab + (size_t)(i * 32 + srow) * KD + kk + scol, As + i * 2048 + wave * 512);
#pragma unroll
        for (int i = 0; i < 4; ++i)
            gl16(Bb + (size_t)(i * 32 + srow) * KD + kk + scol, Bs + i * 2048 + wave * 512);
        __syncthreads();
#pragma unroll
        for (int t = 0; t < 2; ++t) {
            short8 af[4], bfr[4];
#pragma unroll
            for (int mi = 0; mi < 4; ++mi)
                af[mi] = *(const short8*)&As[(wm + mi * 16 + l15) * 64 + t * 32 + qd * 8];
#pragma unroll
            for (int ni = 0; ni < 4; ++ni)
                bfr[ni] = *(const short8*)&Bs[(wn + ni * 16 + l15) * 64 + t * 32 + qd * 8];
#pragma unroll
            for (int mi = 0; mi < 4; ++mi)
#pragma unroll
                for (int ni = 0; ni < 4; ++ni)
                    acc[mi][ni] = __builtin_amdgcn_mfma_f32_16x16x32_bf16(af[mi], bfr[ni],
                                                                          acc[mi][ni], 0, 0, 0);
        }
    }

    if (EPI == 2) {
        float* C = (float*)Cout;
#pragma unroll
        for (int mi = 0; mi < 4; ++mi)
#pragma unroll
            for (int ni = 0; ni < 4; ++ni) {
                const int rbase = row0 + wm + mi * 16 + qd * 4;
                const int col = col0 + wn + ni * 16 + l15;
                const float bsv = bias[col];
#pragma unroll
                for (int r = 0; r < 4; ++r)
                    __builtin_nontemporal_store(acc[mi][ni][r] + bsv,
                                                &C[(size_t)(rbase + r) * NC + col]);
            }
    } else if (EPI == 0) {
        unsigned short* C = (unsigned short*)Cout;
#pragma unroll
        for (int mi = 0; mi < 4; ++mi)
#pragma unroll
            for (int ni = 0; ni < 4; ++ni) {
                const int rbase = row0 + wm + mi * 16 + qd * 4;
                const int col = col0 + wn + ni * 16 + l15;
#pragma unroll
                for (int r = 0; r < 4; ++r)
                    C[(size_t)(rbase + r) * NC + col] = f2b(elu1(acc[mi][ni][r]));
            }
    } else {  // EPI == 3: transposed bf16 via LDS tile
        __syncthreads();  // K-loop LDS reads done before tile reuse
#pragma unroll
        for (int mi = 0; mi < 4; ++mi)
#pragma unroll
            for (int ni = 0; ni < 4; ++ni) {
                const int rb = wm + mi * 16 + qd * 4;
                const int cl = wn + ni * 16 + l15;
                const bool act = (col0 + cl) < DIMSZ;
                ushort4v o;
#pragma unroll
                for (int r = 0; r < 4; ++r) {
                    float v = acc[mi][ni][r];
                    o[r] = f2b(act ? elu1(v) : v);
                }
                *(ushort4v*)&buf[cl * 136 + rb] = o;
            }
        __syncthreads();
        unsigned short* CT = (unsigned short*)Cout;
        const int c0 = tid >> 4, rr = (tid & 15) * 8;
#pragma unroll
        for (int p = 0; p < 8; ++p) {
            const int col = c0 + p * 16;
            ushort8v v = *(const ushort8v*)&buf[col * 136 + rr];
            __builtin_nontemporal_store(v,
                                        (ushort8v*)&CT[(size_t)(col0 + col) * MTOT + row0 + rr]);
        }
    }
}

// ---------------------------------------------------------------------------
// kv state via MFMA: kv[bh][d][m] = sum_n k[n,d]*v[n,m], ksum fused.
// kvpT[768][MTOT] bf16 (k rows [0,384), v rows [384,768)).
// ---------------------------------------------------------------------------
__global__ __launch_bounds__(256) void kv_state_mfma(const unsigned short* __restrict__ kvpT,
                                                     float* __restrict__ pkv,
                                                     float* __restrict__ pks) {
    __shared__ float kvLDS[4096];
    __shared__ float ksLDS[64];
    const int bx = blockIdx.x;
    const int bh = bx >> 4, ch = bx & 15;
    const int b = bh / HEADS, h = bh % HEADS;
    const int tid = threadIdx.x;
    const int lane = tid & 63, wave = tid >> 6;
    const int l15 = lane & 15, qd = lane >> 4;
    const size_t nbase = (size_t)b * SEQ + ch * 256 + wave * 64;
    const unsigned short* kbase = kvpT + (size_t)(h * 64) * MTOT + nbase;
    const unsigned short* vbase = kvpT + (size_t)(DIMSZ + h * 64) * MTOT + nbase;

    floatx4 zero = {0.f, 0.f, 0.f, 0.f};
    floatx4 acc[4][4];
#pragma unroll
    for (int i = 0; i < 4; ++i)
#pragma unroll
        for (int j = 0; j < 4; ++j) acc[i][j] = zero;
    float ksa[4] = {};

#pragma unroll
    for (int t = 0; t < 2; ++t) {
        short8 af[4], bfr[4];
#pragma unroll
        for (int mi = 0; mi < 4; ++mi)
            af[mi] = *(const short8*)&kbase[(size_t)(mi * 16 + l15) * MTOT + t * 32 + qd * 8];
#pragma unroll
        for (int ni = 0; ni < 4; ++ni)
            bfr[ni] = *(const short8*)&vbase[(size_t)(ni * 16 + l15) * MTOT + t * 32 + qd * 8];
#pragma unroll
        for (int mi = 0; mi < 4; ++mi) {
#pragma unroll
            for (int j = 0; j < 8; ++j) ksa[mi] += b2f((unsigned short)af[mi][j]);
#pragma unroll
            for (int ni = 0; ni < 4; ++ni)
                acc[mi][ni] =
                    __builtin_amdgcn_mfma_f32_16x16x32_bf16(af[mi], bfr[ni], acc[mi][ni], 0, 0, 0);
        }
    }
#pragma unroll
    for (int mi = 0; mi < 4; ++mi) {
        float v = ksa[mi];
        v += __shfl_xor(v, 16);
        v += __shfl_xor(v, 32);
        ksa[mi] = v;
    }
    for (int w = 0; w < 4; ++w) {
        if (wave == w) {
#pragma unroll
            for (int mi = 0; mi < 4; ++mi)
#pragma unroll
                for (int ni = 0; ni < 4; ++ni)
#pragma unroll
                    for (int r = 0; r < 4; ++r) {
                        const int idx = (mi * 16 + qd * 4 + r) * 64 + ni * 16 + l15;
                        if (w == 0) kvLDS[idx] = acc[mi][ni][r];
                        else kvLDS[idx] += acc[mi][ni][r];
                    }
            if (lane < 16) {
#pragma unroll
                for (int mi = 0; mi < 4; ++mi) {
                    if (w == 0) ksLDS[mi * 16 + lane] = ksa[mi];
                    else ksLDS[mi * 16 + lane] += ksa[mi];
                }
            }
        }
        __syncthreads();
    }
    const int base = tid * 16;
#pragma unroll
    for (int i = 0; i < 16; i += 4)
        *(float4*)&pkv[(size_t)bx * 4096 + base + i] = *(float4*)&kvLDS[base + i];
    if (tid < 64) pks[bx * 64 + tid] = ksLDS[tid];
}

// ---------------------------------------------------------------------------
// reduce 16 partials per bh -> kv_g fp32, ksum_g fp32
// ---------------------------------------------------------------------------
__global__ __launch_bounds__(256) void kv_reduce(const float* __restrict__ pkv,
                                                 const float* __restrict__ pks,
                                                 float* __restrict__ kv_g,
                                                 float* __restrict__ ksum_g) {
    const int bh = blockIdx.x;
    const int tid = threadIdx.x;
    for (int i0 = tid * 4; i0 < 4096; i0 += 1024) {
        float4 s = {0.f, 0.f, 0.f, 0.f};
#pragma unroll
        for (int c = 0; c < 16; ++c) {
            float4 p = *(const float4*)&pkv[(size_t)(bh * 16 + c) * 4096 + i0];
            s.x += p.x; s.y += p.y; s.z += p.z; s.w += p.w;
        }
        *(float4*)&kv_g[(size_t)bh * 4096 + i0] = s;
    }
    if (tid < 64) {
        float s = 0.f;
#pragma unroll
        for (int c = 0; c < 16; ++c) s += pks[(bh * 16 + c) * 64 + tid];
        ksum_g[bh * 64 + tid] = s;
    }
}

// ---------------------------------------------------------------------------
// attn[n, h*64+m] = z_n * sum_d q[n,d] kv[bh][d][m]  (MFMA, z fused, in-place)
// ---------------------------------------------------------------------------
__global__ __launch_bounds__(256) void attn_mfma(const unsigned short* __restrict__ q,
                                                 const float* __restrict__ kv_g,
                                                 const float* __restrict__ ksum_g,
                                                 unsigned short* __restrict__ attn) {
    __shared__ __align__(16) unsigned short kvbs[64 * 72];  // [m][d], pad 72
    __shared__ float ksh[64];
    __shared__ float zsh[256];
    const int bx = blockIdx.x;
    const int bh = bx >> 4;
    const int rt = bx & 15;
    const int b = bh / HEADS, h = bh % HEADS;
    const int tid = threadIdx.x;
    const int lane = tid & 63, wave = tid >> 6;
    const int l15 = lane & 15, qd = lane >> 4;
#pragma unroll
    for (int i = 0; i < 16; ++i) {
        int e = i * 256 + tid;
        int d = e >> 6, m = e & 63;
        kvbs[m * 72 + d] = f2b(kv_g[(size_t)bh * 4096 + e]);
    }
    if (tid < 64) ksh[tid] = ksum_g[bh * 64 + tid];
    __syncthreads();
    const size_t rowbase = (size_t)b * SEQ + rt * 256;
    floatx4 zero = {0.f, 0.f, 0.f, 0.f};
    floatx4 acc[4][4];
#pragma unroll
    for (int i = 0; i < 4; ++i)
#pragma unroll
        for (int j = 0; j < 4; ++j) acc[i][j] = zero;
    float zp[4] = {};
#pragma unroll
    for (int ks = 0; ks < 2; ++ks) {
        short8 bfr[4];
#pragma unroll
        for (int ni = 0; ni < 4; ++ni)
            bfr[ni] = *(const short8*)&kvbs[(ni * 16 + l15) * 72 + ks * 32 + qd * 8];
#pragma unroll
        for (int mi = 0; mi < 4; ++mi) {
            short8 af = *(const short8*)&q[(rowbase + wave * 64 + mi * 16 + l15) * KD + h * 64 +
                                           ks * 32 + qd * 8];
#pragma unroll
            for (int j = 0; j < 8; ++j)
                zp[mi] += b2f((unsigned short)af[j]) * ksh[ks * 32 + qd * 8 + j];
#pragma unroll
            for (int ni = 0; ni < 4; ++ni)
                acc[mi][ni] =
                    __builtin_amdgcn_mfma_f32_16x16x32_bf16(af, bfr[ni], acc[mi][ni], 0, 0, 0);
        }
    }
#pragma unroll
    for (int mi = 0; mi < 4; ++mi) {
        float v = zp[mi];
        v += __shfl_xor(v, 16);
        v += __shfl_xor(v, 32);
        if (lane < 16) zsh[wave * 64 + mi * 16 + lane] = 1.f / (v + 1e-6f);
    }
    __syncthreads();
#pragma unroll
    for (int mi = 0; mi < 4; ++mi) {
#pragma unroll
        for (int ni = 0; ni < 4; ++ni) {
            const int rl = wave * 64 + mi * 16 + qd * 4;
            const int col = h * 64 + ni * 16 + l15;
#pragma unroll
            for (int r = 0; r < 4; ++r) {
                float v = acc[mi][ni][r] * zsh[rl + r];
                attn[(rowbase + rl + r) * KD + col] = f2b(v);
            }
        }
    }
}

extern "C" void kernel_launch(void* const* d_in, const int* in_sizes, int n_in,
                              void* d_out, int out_size, void* d_ws, size_t ws_size,
                              hipStream_t stream) {
    const float* x_q = (const float*)d_in[0];
    const float* x_kv = (const float*)d_in[1];
    const float* Wq = (const float*)d_in[2];
    const float* Wkv = (const float*)d_in[3];
    const float* Wout = (const float*)d_in[4];
    const float* bout = (const float*)d_in[5];
    float* out = (float*)d_out;

    char* ws = (char*)d_ws;
    // x_bf [0,25.2MB): xkv_bf, then (after kv-proj consumed it) xq_bf.
    // kvpT [25.2,75.5): dead after kv_state_mfma; its upper half [50.3,75.5)
    // is then reused as q_bf.
    unsigned short* x_bf = (unsigned short*)(ws + 0);          // 25.2 MB (alias kv->q)
    unsigned short* kvpT = (unsigned short*)(ws + 25165824);   // 50.3 MB [768][32768]
    unsigned short* q_bf = (unsigned short*)(ws + 50331648);   // alias (attn in-place)
    unsigned short* WqT = (unsigned short*)(ws + 75497472);    // 0.29 MB
    unsigned short* WkvT = (unsigned short*)(ws + 75792384);   // 0.59 MB
    unsigned short* WoutT = (unsigned short*)(ws + 76382208);  // 0.29 MB
    float* kv = (float*)(ws + 76677120);                       // 0.79 MB
    float* ksum = (float*)(ws + 77463552);                     // 12 KB
    float* pkv = (float*)(ws + 77475840);                      // 12.6 MB
    float* pks = (float*)(ws + 90058752);                      // 0.19 MB

    dim3 blk(256);
    conv_wt<<<dim3(12, 12), blk, 0, stream>>>(Wq, WqT, DIMSZ);
    conv_wt<<<dim3(24, 12), blk, 0, stream>>>(Wkv, WkvT, 2 * DIMSZ);
    conv_wt<<<dim3(12, 12), blk, 0, stream>>>(Wout, WoutT, DIMSZ);
    // x_kv -> bf16, kv-projection -> TRANSPOSED kvpT
    conv_bf16<<<dim3(6144), blk, 0, stream>>>(x_kv, x_bf);
    gemm_bt<3, 768><<<dim3(1536), blk, 0, stream>>>(x_bf, WkvT, kvpT, nullptr);
    // kv state + ksum via MFMA (partials), then reduce
    kv_state_mfma<<<dim3(768), blk, 0, stream>>>(kvpT, pkv, pks);
    kv_reduce<<<dim3(48), blk, 0, stream>>>(pkv, pks, kv, ksum);
    // x_q -> bf16 (x_bf dead after kv-proj), q-projection into dead kvpT space
    conv_bf16<<<dim3(6144), blk, 0, stream>>>(x_q, x_bf);
    gemm_bt<0, 384><<<dim3(768), blk, 0, stream>>>(x_bf, WqT, q_bf, nullptr);
    // attn = (q @ kv) * z   (z fused; in-place over q)
    attn_mfma<<<dim3(768), blk, 0, stream>>>(q_bf, kv, ksum, q_bf);
    // out = attn @ Wout + bout
    gemm_bt<2, 384><<<dim3(768), blk, 0, stream>>>(q_bf, WoutT, out, bout);
}

// Round 6
// 262.915 us; speedup vs baseline: 1.0805x; 1.0539x over previous
//
#include <hip/hip_runtime.h>
#include <math.h>

#define BATCH 8
#define SEQ 4096
#define DIMSZ 384
#define HEADS 6
#define DH 64
#define MTOT (BATCH * SEQ) /* 32768 */
#define KD 384

typedef short short8 __attribute__((ext_vector_type(8)));
typedef float floatx4 __attribute__((ext_vector_type(4)));
typedef unsigned short ushort4v __attribute__((ext_vector_type(4)));
typedef unsigned short ushort8v __attribute__((ext_vector_type(8)));

__device__ __forceinline__ float elu1(float x) { return x > 0.f ? x + 1.f : __expf(x); }

__device__ __forceinline__ unsigned short f2b(float f) {
    unsigned int u = __float_as_uint(f);
    u = (u + 0x7fffu + ((u >> 16) & 1u)) >> 16;
    return (unsigned short)u;
}
__device__ __forceinline__ float b2f(unsigned short u) {
    return __uint_as_float(((unsigned int)u) << 16);
}

__device__ __forceinline__ void gl16(const void* g, void* l) {
    __builtin_amdgcn_global_load_lds((const __attribute__((address_space(1))) unsigned int*)g,
                                     (__attribute__((address_space(3))) unsigned int*)l, 16, 0, 0);
}

// ---------------------------------------------------------------------------
// fp32 -> bf16 bulk convert (8 elems/thread) — pure-BW pass.
// ---------------------------------------------------------------------------
__global__ __launch_bounds__(256) void conv_bf16(const float* __restrict__ src,
                                                 unsigned short* __restrict__ dst) {
    size_t i = ((size_t)blockIdx.x * 256 + threadIdx.x) * 8;
    float4 a = *(const float4*)&src[i];
    float4 b = *(const float4*)&src[i + 4];
    ushort8v o;
    o[0] = f2b(a.x); o[1] = f2b(a.y); o[2] = f2b(a.z); o[3] = f2b(a.w);
    o[4] = f2b(b.x); o[5] = f2b(b.y); o[6] = f2b(b.z); o[7] = f2b(b.w);
    *(ushort8v*)&dst[i] = o;
}

// ---------------------------------------------------------------------------
// All three weights: W[384][N] fp32 -> WT[N][384] bf16 (transpose + convert).
// Flat grid: bx 0..11 -> Wq, 12..35 -> Wkv, 36..47 -> Wout; by = k-tile.
// ---------------------------------------------------------------------------
__global__ __launch_bounds__(256) void conv_wt3(const float* __restrict__ Wq,
                                                const float* __restrict__ Wkv,
                                                const float* __restrict__ Wout,
                                                unsigned short* __restrict__ WqT,
                                                unsigned short* __restrict__ WkvT,
                                                unsigned short* __restrict__ WoutT) {
    __shared__ float tile[32][33];
    int bx = blockIdx.x;
    const float* W;
    unsigned short* WT;
    int N;
    if (bx < 12) { W = Wq; WT = WqT; N = DIMSZ; }
    else if (bx < 36) { W = Wkv; WT = WkvT; N = 2 * DIMSZ; bx -= 12; }
    else { W = Wout; WT = WoutT; N = DIMSZ; bx -= 36; }
    const int n0 = bx * 32, k0 = blockIdx.y * 32;
    const int tx = threadIdx.x & 31, ty = threadIdx.x >> 5;  // 32 x 8
#pragma unroll
    for (int i = 0; i < 32; i += 8) tile[ty + i][tx] = W[(size_t)(k0 + ty + i) * N + n0 + tx];
    __syncthreads();
#pragma unroll
    for (int i = 0; i < 32; i += 8)
        WT[(size_t)(n0 + ty + i) * KD + k0 + tx] = f2b(tile[tx][ty + i]);
}

// ---------------------------------------------------------------------------
// MFMA GEMM: A[M][384] bf16 row-major, BT[N][384] bf16, 128x128 tile, BK=64,
// global_load_lds staging with XOR-swizzled LDS layout:
//   logical 16B chunk j of row r lives at physical chunk j^(r&7).
//   (BK=64 row stride = 128 B = all 32 banks, so unswizzled b128 fragment
//    reads were 16-way bank conflicts — R5's 7.67M SQ_LDS_BANK_CONFLICT.)
// XCD swizzle: xcd=id&7 owns row-tile group -> A fetched once per XCD L2.
// EPI: 0 = elu+1 -> bf16 row-major ; 2 = +bias -> fp32 (nt) ;
//      3 = (col<384 ? elu+1 : id) -> bf16 TRANSPOSED CT[col][MTOT] via LDS
// ---------------------------------------------------------------------------
template <int EPI, int NC>
__global__ __launch_bounds__(256) void gemm_bt(const unsigned short* __restrict__ A,
                                               const unsigned short* __restrict__ BT,
                                               void* __restrict__ Cout,
                                               const float* __restrict__ bias) {
    __shared__ __align__(16) unsigned short buf[17408];  // As[128][64] | Bs[128][64]; epi tile
    unsigned short* As = buf;
    unsigned short* Bs = buf + 8192;
    const int tid = threadIdx.x;
    const int lane = tid & 63, wave = tid >> 6;
    const int l15 = lane & 15, qd = lane >> 4;
    constexpr int NXT = NC / 128;
    const int fid = blockIdx.x;
    const int xcd = fid & 7;
    const int s = fid >> 3;
    const int row0 = (xcd * 32 + s / NXT) * 128;
    const int col0 = (s % NXT) * 128;
    const int wm = (wave & 1) * 64, wn = (wave >> 1) * 64;

    const unsigned short* Ab = A + (size_t)row0 * KD;
    const unsigned short* Bb = BT + (size_t)col0 * KD;
    const int srow = tid >> 3;                              // 0..31 (row within 32-row group)
    const int scol = (((tid & 7) ^ (srow & 7)) * 8);        // XOR-swizzled source chunk

    floatx4 zero = {0.f, 0.f, 0.f, 0.f};
    floatx4 acc[4][4];
#pragma unroll
    for (int i = 0; i < 4; ++i)
#pragma unroll
        for (int j = 0; j < 4; ++j) acc[i][j] = zero;

    const int sw = l15 & 7;  // read-side swizzle key (row & 7)
    for (int kk = 0; kk < KD; kk += 64) {
        __syncthreads();
#pragma unroll
        for (int i = 0; i < 4; ++i)
            gl16(Ab + (size_t)(i * 32 + srow) * KD + kk + scol, As + i * 2048 + wave * 512);
#pragma unroll
        for (int i = 0; i < 4; ++i)
            gl16(Bb + (size_t)(i * 32 + srow) * KD + kk + scol, Bs + i * 2048 + wave * 512);
        __syncthreads();
#pragma unroll
        for (int t = 0; t < 2; ++t) {
            const int chnk = ((t * 4 + qd) ^ sw) * 8;
            short8 af[4], bfr[4];
#pragma unroll
            for (int mi = 0; mi < 4; ++mi)
                af[mi] = *(const short8*)&As[(wm + mi * 16 + l15) * 64 + chnk];
#pragma unroll
            for (int ni = 0; ni < 4; ++ni)
                bfr[ni] = *(const short8*)&Bs[(wn + ni * 16 + l15) * 64 + chnk];
#pragma unroll
            for (int mi = 0; mi < 4; ++mi)
#pragma unroll
                for (int ni = 0; ni < 4; ++ni)
                    acc[mi][ni] = __builtin_amdgcn_mfma_f32_16x16x32_bf16(af[mi], bfr[ni],
                                                                          acc[mi][ni], 0, 0, 0);
        }
    }

    if (EPI == 2) {
        float* C = (float*)Cout;
#pragma unroll
        for (int mi = 0; mi < 4; ++mi)
#pragma unroll
            for (int ni = 0; ni < 4; ++ni) {
                const int rbase = row0 + wm + mi * 16 + qd * 4;
                const int col = col0 + wn + ni * 16 + l15;
                const float bsv = bias[col];
#pragma unroll
                for (int r = 0; r < 4; ++r)
                    __builtin_nontemporal_store(acc[mi][ni][r] + bsv,
                                                &C[(size_t)(rbase + r) * NC + col]);
            }
    } else if (EPI == 0) {
        unsigned short* C = (unsigned short*)Cout;
#pragma unroll
        for (int mi = 0; mi < 4; ++mi)
#pragma unroll
            for (int ni = 0; ni < 4; ++ni) {
                const int rbase = row0 + wm + mi * 16 + qd * 4;
                const int col = col0 + wn + ni * 16 + l15;
#pragma unroll
                for (int r = 0; r < 4; ++r)
                    C[(size_t)(rbase + r) * NC + col] = f2b(elu1(acc[mi][ni][r]));
            }
    } else {  // EPI == 3: transposed bf16 via LDS tile
        __syncthreads();  // K-loop LDS reads done before tile reuse
#pragma unroll
        for (int mi = 0; mi < 4; ++mi)
#pragma unroll
            for (int ni = 0; ni < 4; ++ni) {
                const int rb = wm + mi * 16 + qd * 4;
                const int cl = wn + ni * 16 + l15;
                const bool act = (col0 + cl) < DIMSZ;
                ushort4v o;
#pragma unroll
                for (int r = 0; r < 4; ++r) {
                    float v = acc[mi][ni][r];
                    o[r] = f2b(act ? elu1(v) : v);
                }
                *(ushort4v*)&buf[cl * 136 + rb] = o;
            }
        __syncthreads();
        unsigned short* CT = (unsigned short*)Cout;
        const int c0 = tid >> 4, rr = (tid & 15) * 8;
#pragma unroll
        for (int p = 0; p < 8; ++p) {
            const int col = c0 + p * 16;
            ushort8v v = *(const ushort8v*)&buf[col * 136 + rr];
            __builtin_nontemporal_store(v,
                                        (ushort8v*)&CT[(size_t)(col0 + col) * MTOT + row0 + rr]);
        }
    }
}

// ---------------------------------------------------------------------------
// kv state via MFMA: kv[bh][d][m] = sum_n k[n,d]*v[n,m], ksum fused.
// kvpT[768][MTOT] bf16 (k rows [0,384), v rows [384,768)).
// ---------------------------------------------------------------------------
__global__ __launch_bounds__(256) void kv_state_mfma(const unsigned short* __restrict__ kvpT,
                                                     float* __restrict__ pkv,
                                                     float* __restrict__ pks) {
    __shared__ float kvLDS[4096];
    __shared__ float ksLDS[64];
    const int bx = blockIdx.x;
    const int bh = bx >> 4, ch = bx & 15;
    const int b = bh / HEADS, h = bh % HEADS;
    const int tid = threadIdx.x;
    const int lane = tid & 63, wave = tid >> 6;
    const int l15 = lane & 15, qd = lane >> 4;
    const size_t nbase = (size_t)b * SEQ + ch * 256 + wave * 64;
    const unsigned short* kbase = kvpT + (size_t)(h * 64) * MTOT + nbase;
    const unsigned short* vbase = kvpT + (size_t)(DIMSZ + h * 64) * MTOT + nbase;

    floatx4 zero = {0.f, 0.f, 0.f, 0.f};
    floatx4 acc[4][4];
#pragma unroll
    for (int i = 0; i < 4; ++i)
#pragma unroll
        for (int j = 0; j < 4; ++j) acc[i][j] = zero;
    float ksa[4] = {};

#pragma unroll
    for (int t = 0; t < 2; ++t) {
        short8 af[4], bfr[4];
#pragma unroll
        for (int mi = 0; mi < 4; ++mi)
            af[mi] = *(const short8*)&kbase[(size_t)(mi * 16 + l15) * MTOT + t * 32 + qd * 8];
#pragma unroll
        for (int ni = 0; ni < 4; ++ni)
            bfr[ni] = *(const short8*)&vbase[(size_t)(ni * 16 + l15) * MTOT + t * 32 + qd * 8];
#pragma unroll
        for (int mi = 0; mi < 4; ++mi) {
#pragma unroll
            for (int j = 0; j < 8; ++j) ksa[mi] += b2f((unsigned short)af[mi][j]);
#pragma unroll
            for (int ni = 0; ni < 4; ++ni)
                acc[mi][ni] =
                    __builtin_amdgcn_mfma_f32_16x16x32_bf16(af[mi], bfr[ni], acc[mi][ni], 0, 0, 0);
        }
    }
#pragma unroll
    for (int mi = 0; mi < 4; ++mi) {
        float v = ksa[mi];
        v += __shfl_xor(v, 16);
        v += __shfl_xor(v, 32);
        ksa[mi] = v;
    }
    for (int w = 0; w < 4; ++w) {
        if (wave == w) {
#pragma unroll
            for (int mi = 0; mi < 4; ++mi)
#pragma unroll
                for (int ni = 0; ni < 4; ++ni)
#pragma unroll
                    for (int r = 0; r < 4; ++r) {
                        const int idx = (mi * 16 + qd * 4 + r) * 64 + ni * 16 + l15;
                        if (w == 0) kvLDS[idx] = acc[mi][ni][r];
                        else kvLDS[idx] += acc[mi][ni][r];
                    }
            if (lane < 16) {
#pragma unroll
                for (int mi = 0; mi < 4; ++mi) {
                    if (w == 0) ksLDS[mi * 16 + lane] = ksa[mi];
                    else ksLDS[mi * 16 + lane] += ksa[mi];
                }
            }
        }
        __syncthreads();
    }
    const int base = tid * 16;
#pragma unroll
    for (int i = 0; i < 16; i += 4)
        *(float4*)&pkv[(size_t)bx * 4096 + base + i] = *(float4*)&kvLDS[base + i];
    if (tid < 64) pks[bx * 64 + tid] = ksLDS[tid];
}

// ---------------------------------------------------------------------------
// reduce 16 partials per bh -> kv_g fp32, ksum_g fp32
// ---------------------------------------------------------------------------
__global__ __launch_bounds__(256) void kv_reduce(const float* __restrict__ pkv,
                                                 const float* __restrict__ pks,
                                                 float* __restrict__ kv_g,
                                                 float* __restrict__ ksum_g) {
    const int bh = blockIdx.x;
    const int tid = threadIdx.x;
    for (int i0 = tid * 4; i0 < 4096; i0 += 1024) {
        float4 s = {0.f, 0.f, 0.f, 0.f};
#pragma unroll
        for (int c = 0; c < 16; ++c) {
            float4 p = *(const float4*)&pkv[(size_t)(bh * 16 + c) * 4096 + i0];
            s.x += p.x; s.y += p.y; s.z += p.z; s.w += p.w;
        }
        *(float4*)&kv_g[(size_t)bh * 4096 + i0] = s;
    }
    if (tid < 64) {
        float s = 0.f;
#pragma unroll
        for (int c = 0; c < 16; ++c) s += pks[(bh * 16 + c) * 64 + tid];
        ksum_g[bh * 64 + tid] = s;
    }
}

// ---------------------------------------------------------------------------
// attn[n, h*64+m] = z_n * sum_d q[n,d] kv[bh][d][m]  (MFMA, z fused, in-place)
// ---------------------------------------------------------------------------
__global__ __launch_bounds__(256) void attn_mfma(const unsigned short* __restrict__ q,
                                                 const float* __restrict__ kv_g,
                                                 const float* __restrict__ ksum_g,
                                                 unsigned short* __restrict__ attn) {
    __shared__ __align__(16) unsigned short kvbs[64 * 72];  // [m][d], pad 72
    __shared__ float ksh[64];
    __shared__ float zsh[256];
    const int bx = blockIdx.x;
    const int bh = bx >> 4;
    const int rt = bx & 15;
    const int b = bh / HEADS, h = bh % HEADS;
    const int tid = threadIdx.x;
    const int lane = tid & 63, wave = tid >> 6;
    const int l15 = lane & 15, qd = lane >> 4;
#pragma unroll
    for (int i = 0; i < 16; ++i) {
        int e = i * 256 + tid;
        int d = e >> 6, m = e & 63;
        kvbs[m * 72 + d] = f2b(kv_g[(size_t)bh * 4096 + e]);
    }
    if (tid < 64) ksh[tid] = ksum_g[bh * 64 + tid];
    __syncthreads();
    const size_t rowbase = (size_t)b * SEQ + rt * 256;
    floatx4 zero = {0.f, 0.f, 0.f, 0.f};
    floatx4 acc[4][4];
#pragma unroll
    for (int i = 0; i < 4; ++i)
#pragma unroll
        for (int j = 0; j < 4; ++j) acc[i][j] = zero;
    float zp[4] = {};
#pragma unroll
    for (int ks = 0; ks < 2; ++ks) {
        short8 bfr[4];
#pragma unroll
        for (int ni = 0; ni < 4; ++ni)
            bfr[ni] = *(const short8*)&kvbs[(ni * 16 + l15) * 72 + ks * 32 + qd * 8];
#pragma unroll
        for (int mi = 0; mi < 4; ++mi) {
            short8 af = *(const short8*)&q[(rowbase + wave * 64 + mi * 16 + l15) * KD + h * 64 +
                                           ks * 32 + qd * 8];
#pragma unroll
            for (int j = 0; j < 8; ++j)
                zp[mi] += b2f((unsigned short)af[j]) * ksh[ks * 32 + qd * 8 + j];
#pragma unroll
            for (int ni = 0; ni < 4; ++ni)
                acc[mi][ni] =
                    __builtin_amdgcn_mfma_f32_16x16x32_bf16(af, bfr[ni], acc[mi][ni], 0, 0, 0);
        }
    }
#pragma unroll
    for (int mi = 0; mi < 4; ++mi) {
        float v = zp[mi];
        v += __shfl_xor(v, 16);
        v += __shfl_xor(v, 32);
        if (lane < 16) zsh[wave * 64 + mi * 16 + lane] = 1.f / (v + 1e-6f);
    }
    __syncthreads();
#pragma unroll
    for (int mi = 0; mi < 4; ++mi) {
#pragma unroll
        for (int ni = 0; ni < 4; ++ni) {
            const int rl = wave * 64 + mi * 16 + qd * 4;
            const int col = h * 64 + ni * 16 + l15;
#pragma unroll
            for (int r = 0; r < 4; ++r) {
                float v = acc[mi][ni][r] * zsh[rl + r];
                attn[(rowbase + rl + r) * KD + col] = f2b(v);
            }
        }
    }
}

extern "C" void kernel_launch(void* const* d_in, const int* in_sizes, int n_in,
                              void* d_out, int out_size, void* d_ws, size_t ws_size,
                              hipStream_t stream) {
    const float* x_q = (const float*)d_in[0];
    const float* x_kv = (const float*)d_in[1];
    const float* Wq = (const float*)d_in[2];
    const float* Wkv = (const float*)d_in[3];
    const float* Wout = (const float*)d_in[4];
    const float* bout = (const float*)d_in[5];
    float* out = (float*)d_out;

    char* ws = (char*)d_ws;
    // x_bf [0,25.2MB): xkv_bf, then (after kv-proj consumed it) xq_bf.
    // kvpT [25.2,75.5): dead after kv_state_mfma; upper half reused as q_bf.
    unsigned short* x_bf = (unsigned short*)(ws + 0);          // 25.2 MB (alias kv->q)
    unsigned short* kvpT = (unsigned short*)(ws + 25165824);   // 50.3 MB [768][32768]
    unsigned short* q_bf = (unsigned short*)(ws + 50331648);   // alias (attn in-place)
    unsigned short* WqT = (unsigned short*)(ws + 75497472);    // 0.29 MB
    unsigned short* WkvT = (unsigned short*)(ws + 75792384);   // 0.59 MB
    unsigned short* WoutT = (unsigned short*)(ws + 76382208);  // 0.29 MB
    float* kv = (float*)(ws + 76677120);                       // 0.79 MB
    float* ksum = (float*)(ws + 77463552);                     // 12 KB
    float* pkv = (float*)(ws + 77475840);                      // 12.6 MB
    float* pks = (float*)(ws + 90058752);                      // 0.19 MB

    dim3 blk(256);
    conv_wt3<<<dim3(48, 12), blk, 0, stream>>>(Wq, Wkv, Wout, WqT, WkvT, WoutT);
    // x_kv -> bf16, kv-projection -> TRANSPOSED kvpT
    conv_bf16<<<dim3(6144), blk, 0, stream>>>(x_kv, x_bf);
    gemm_bt<3, 768><<<dim3(1536), blk, 0, stream>>>(x_bf, WkvT, kvpT, nullptr);
    // kv state + ksum via MFMA (partials), then reduce
    kv_state_mfma<<<dim3(768), blk, 0, stream>>>(kvpT, pkv, pks);
    kv_reduce<<<dim3(48), blk, 0, stream>>>(pkv, pks, kv, ksum);
    // x_q -> bf16 (x_bf dead after kv-proj), q-projection into dead kvpT space
    conv_bf16<<<dim3(6144), blk, 0, stream>>>(x_q, x_bf);
    gemm_bt<0, 384><<<dim3(768), blk, 0, stream>>>(x_bf, WqT, q_bf, nullptr);
    // attn = (q @ kv) * z   (z fused; in-place over q)
    attn_mfma<<<dim3(768), blk, 0, stream>>>(q_bf, kv, ksum, q_bf);
    // out = attn @ Wout + bout
    gemm_bt<2, 384><<<dim3(768), blk, 0, stream>>>(q_bf, WoutT, out, bout);
}